// Round 5
// baseline (232.232 us; speedup 1.0000x reference)
//
#include <hip/hip_runtime.h>
#include <cstdint>
#include <cstddef>

// ---------------- problem constants ----------------
#define SEQ     2048
#define NBATCH  2
#define CDIM    1024
#define NHEAD   16
#define HDIM    64
#define MTOT    (NBATCH*SEQ)   // 4096 rows
#define C3      (3*CDIM)       // 3072
#define LOG2E   1.44269504088896340736f
#define QKSCALE (0.125f*LOG2E) // HDIM^-0.5, exp2-domain fold
#define LN_EPS  1e-5f

typedef unsigned short u16;
typedef short s16x8 __attribute__((ext_vector_type(8)));   // 8 bf16 (4 VGPR)
typedef float f32x4  __attribute__((ext_vector_type(4)));
typedef float f32x16 __attribute__((ext_vector_type(16)));

static __device__ __forceinline__ f32x4 mfma16(s16x8 a, s16x8 b, f32x4 c) {
  return __builtin_amdgcn_mfma_f32_16x16x32_bf16(a, b, c, 0, 0, 0);
}
static __device__ __forceinline__ f32x16 mfma32(s16x8 a, s16x8 b, f32x16 c) {
  return __builtin_amdgcn_mfma_f32_32x32x16_bf16(a, b, c, 0, 0, 0);
}
static __device__ __forceinline__ float b2f(u16 v) {
  return __uint_as_float(((unsigned)v) << 16);
}
static __device__ __forceinline__ u16 f2b(float f) {   // RNE fp32->bf16
  unsigned u = __float_as_uint(f);
  u = u + 0x7fffu + ((u >> 16) & 1u);
  return (u16)(u >> 16);
}
// raw v_exp_f32 (2^x). Inputs bounded |x|<=12 here -> no specials.
static __device__ __forceinline__ float fexp2(float x) {
  float r;
  asm("v_exp_f32 %0, %1" : "=v"(r) : "v"(x));
  return r;
}

// async global->LDS, 16B per lane, LDS dst = wave-uniform base + lane*16
#define G2L16(g, l) __builtin_amdgcn_global_load_lds( \
    (__attribute__((address_space(1))) void*)(g),     \
    (__attribute__((address_space(3))) void*)(l), 16, 0, 0)

// ---------------- fused fp32 -> bf16 casts (x, qkv_w, proj_w) ---------------
#define XSEG   (MTOT*CDIM/8)        // 524288 chunks of 8
#define W1SEG  (C3*CDIM/8)          // 393216
#define W2SEG  (CDIM*CDIM/8)        // 131072
__global__ __launch_bounds__(256) void cast_all(
    const float* __restrict__ x, const float* __restrict__ w1,
    const float* __restrict__ w2, u16* __restrict__ xb,
    u16* __restrict__ wqkv, u16* __restrict__ wproj)
{
  int i = blockIdx.x * 256 + threadIdx.x;
  const float* src; u16* dst; int off;
  if (i < XSEG)              { src = x;  dst = xb;    off = i; }
  else if (i < XSEG + W1SEG) { src = w1; dst = wqkv;  off = i - XSEG; }
  else                       { src = w2; dst = wproj; off = i - XSEG - W1SEG; }
  float4 a = ((const float4*)src)[2*off];
  float4 b = ((const float4*)src)[2*off+1];
  union { u16 u[8]; uint4 v; } r;
  r.u[0]=f2b(a.x); r.u[1]=f2b(a.y); r.u[2]=f2b(a.z); r.u[3]=f2b(a.w);
  r.u[4]=f2b(b.x); r.u[5]=f2b(b.y); r.u[6]=f2b(b.z); r.u[7]=f2b(b.w);
  ((uint4*)dst)[off] = r.v;
}

// ---------------- NT GEMM: C[M][N] = A[M][K] * B[N][K]^T  (bf16 MFMA) ------
// m97 structure: 128x128 tile, 4 waves (2x2), BK=64, global_load_lds w=16.
// T2 XOR-swizzle (chunk ^= row&7) via pre-swizzled global source (m173);
// kills the 128B-row 16-way ds_read conflict (R4: 9.4M conflicts/dispatch).
// Grid is (Mtiles, Ntiles): linear dispatch round-robins M -> each XCD's
// A-panels (m == xcd mod 8, 1 MB) stay L2-resident; B streams via L3.
template<bool WRITE_BF16, bool BIAS>
__global__ __launch_bounds__(256) void gemm_nt(
    const u16* __restrict__ A, const u16* __restrict__ Bm,
    void* __restrict__ Cout, const float* __restrict__ bias,
    int M, int Nn, int K)
{
  __shared__ u16 As[128*64];   // [row][64] swizzled, 16KB
  __shared__ u16 Bs[128*64];
  const int tid = threadIdx.x;
  const int wave = tid >> 6, lane = tid & 63;
  const int l15 = lane & 15, l4 = lane >> 4;
  const int m0 = blockIdx.x * 128, n0 = blockIdx.y * 128;
  const int wr = (wave >> 1) * 64, wc = (wave & 1) * 64;
  f32x4 acc[4][4] = {};

  for (int k0 = 0; k0 < K; k0 += 64) {
    if (k0) __syncthreads();                 // prev reads done before restage
#pragma unroll
    for (int i = 0; i < 4; ++i) {            // 4 issues/wave for A and for B
      int ci  = (i*4 + wave)*64 + lane;      // 16B-chunk index 0..1023
      int row = ci >> 3, ch = ci & 7;        // 8 chunks per 128B row
      int chs = ch ^ (row & 7);              // pre-swizzled source
      const u16* ga = A  + (size_t)(m0 + row)*K + k0 + chs*8;
      const u16* gb = Bm + (size_t)(n0 + row)*K + k0 + chs*8;
      G2L16(ga, As + (i*4 + wave)*512);
      G2L16(gb, Bs + (i*4 + wave)*512);
    }
    __syncthreads();                          // barrier drains vmcnt

#pragma unroll
    for (int kk = 0; kk < 2; ++kk) {
      s16x8 af[4], bf[4];
#pragma unroll
      for (int r = 0; r < 4; ++r) {
        int row = wr + r*16 + l15;
        af[r] = *(const s16x8*)(As + row*64 + (((kk*4 + l4) ^ (row & 7))*8));
      }
#pragma unroll
      for (int c = 0; c < 4; ++c) {
        int row = wc + c*16 + l15;
        bf[c] = *(const s16x8*)(Bs + row*64 + (((kk*4 + l4) ^ (row & 7))*8));
      }
#pragma unroll
      for (int r = 0; r < 4; ++r)
#pragma unroll
        for (int c = 0; c < 4; ++c)
          acc[r][c] = mfma16(af[r], bf[c], acc[r][c]);
    }
  }

  // C/D layout: row=(lane>>4)*4+reg, col=lane&15
#pragma unroll
  for (int r = 0; r < 4; ++r)
#pragma unroll
    for (int c = 0; c < 4; ++c) {
      int row = m0 + wr + r*16 + l4*4;
      int col = n0 + wc + c*16 + l15;
#pragma unroll
      for (int q = 0; q < 4; ++q) {
        float v = acc[r][c][q];
        if (BIAS) v += bias[col];
        if (WRITE_BF16) ((u16*)Cout)[(size_t)(row + q)*Nn + col] = f2b(v);
        else           ((float*)Cout)[(size_t)(row + q)*Nn + col] = v;
      }
    }
}

// ---------------- per-head LayerNorm of q,k (wave per (row,head)) ----------
// qkv[m][3072] bf16 -> Qs = LN(q)*QKSCALE (exp2-domain), Kn = LN(k), bf16.
// k-centering is softmax-invariant -> skipped.
__global__ __launch_bounds__(256) void ln_qk(
    const u16* __restrict__ qkv,
    const float* __restrict__ qw, const float* __restrict__ qb,
    const float* __restrict__ kw, const float* __restrict__ kb,
    u16* __restrict__ Qs, u16* __restrict__ Kn)
{
  int gw   = blockIdx.x * 4 + (threadIdx.x >> 6);   // global wave id
  int lane = threadIdx.x & 63;                      // = d
  int m = gw >> 4, h = gw & 15;
  const u16* rowp = qkv + (size_t)m*C3 + h*HDIM + lane;
  int b = m >> 11, n = m & 2047;
  size_t o = ((size_t)(b*NHEAD + h)*SEQ + n)*HDIM + lane;

  float wq = qw[lane], bq = qb[lane], wk = kw[lane], bk = kb[lane];
  float xq = b2f(rowp[0]);
  float xk = b2f(rowp[CDIM]);
  float sq = xq, s2q = xq*xq, sk = xk, s2k = xk*xk;
#pragma unroll
  for (int off = 32; off; off >>= 1) {
    sq += __shfl_xor(sq, off, 64);  s2q += __shfl_xor(s2q, off, 64);
    sk += __shfl_xor(sk, off, 64);  s2k += __shfl_xor(s2k, off, 64);
  }
  float muq = sq*(1.f/64.f), varq = s2q*(1.f/64.f) - muq*muq;
  float muk = sk*(1.f/64.f), vark = s2k*(1.f/64.f) - muk*muk;
  float yq = (xq - muq) * (1.f/sqrtf(varq + LN_EPS)) * wq + bq;
  float yk = (xk - muk) * (1.f/sqrtf(vark + LN_EPS)) * wk + bk;
  Qs[o] = f2b(yq * QKSCALE);
  Kn[o] = f2b(yk);
}

// ---------------- V transpose: qkv v-part -> Vt [B,H,D,N] bf16 -------------
__global__ __launch_bounds__(256) void v_transpose(
    const u16* __restrict__ qkv, u16* __restrict__ Vt)
{
  __shared__ u16 t[64][80];            // +16 pad
  int bh = blockIdx.x, j0 = blockIdx.y * 64;
  int b = bh >> 4, h = bh & 15;
  int tid = threadIdx.x;
  int nl = tid >> 2, ch = tid & 3;
  const u16* src = qkv + (size_t)(b*SEQ + j0 + nl)*C3 + 2*CDIM + h*HDIM + ch*16;
  *(uint4*)&t[nl][ch*16]     = *(const uint4*)src;
  *(uint4*)&t[nl][ch*16 + 8] = *(const uint4*)(src + 8);
  __syncthreads();
  int d = tid >> 2, nc = tid & 3;
  u16 o[16];
#pragma unroll
  for (int i = 0; i < 16; ++i) o[i] = t[nc*16 + i][d];
  u16* dst = Vt + ((size_t)(bh*HDIM + d))*SEQ + j0 + nc*16;
  *(uint4*)dst       = *(uint4*)&o[0];
  *(uint4*)(dst + 8) = *(uint4*)&o[8];
}

// ---------------- flash attention (32x32 MFMA, V direct-to-reg) -------------
// 4 waves x QBLK=32 q-rows = 128 q/block; KV tiles of 64; grid (16, 32).
// XCD chunked swizzle: XCD x owns bh [4x,4x+4) -> 2 MB KV per XCD, L2-fit.
// K: 3-buf LDS via global_load_lds (XOR-swizzled source), 1 barrier/tile.
// V: loaded straight global->VGPR one tile ahead (8x16B/lane, L2-resident);
// the compiler's own counted vmcnt before PV retires K stages by issue order,
// so no manual in-loop waitcnt is needed (prologue vmcnt(8) only).
// Swapped QK^T + no-max exp2 softmax (LN bounds |logit|<=8) as R3/R4.
__global__ __launch_bounds__(256) void flash_attn(
    const u16* __restrict__ Qs, const u16* __restrict__ Kn,
    const u16* __restrict__ Vt, u16* __restrict__ Oa)
{
  __shared__ u16 Kt[3][64*64];     // [kv][d] swizzled, 3x8KB
  const int tid = threadIdx.x, wave = tid >> 6, lane = tid & 63;
  const int l31 = lane & 31, hi = lane >> 5;
  const int bid0 = blockIdx.x + blockIdx.y*16;     // 512 blocks
  const int nid  = (bid0 & 7)*64 + (bid0 >> 3);    // chunked XCD swizzle
  const int bh   = nid >> 4;
  const int q0   = (nid & 15)*128 + wave*32;
  const int sw = l31 & 7;

  // Q^T B-fragments: lane holds Q[q0+l31][ks*16 + hi*8 + j], j=0..7
  const u16* Qrow = Qs + ((size_t)bh*SEQ + q0 + l31)*HDIM + hi*8;
  s16x8 qf[4];
#pragma unroll
  for (int ks = 0; ks < 4; ++ks)
    qf[ks] = *(const s16x8*)(Qrow + ks*16);

  f32x16 o0 = {}, o1 = {};
  float l_run = 0.f;

  const u16* Kg = Kn + (size_t)bh*SEQ*HDIM;
  const u16* Vg = Vt + (size_t)bh*HDIM*SEQ;

  auto STAGEK = [&](int jb, int buf) {     // 2 gload_lds per wave
#pragma unroll
    for (int i = 0; i < 2; ++i) {
      int ci = (i*4 + wave)*64 + lane;
      int row = ci >> 3, ch = ci & 7;
      int chs = ch ^ (row & 7);               // pre-swizzled source
      G2L16(Kg + (size_t)(jb + row)*HDIM + chs*8, Kt[buf] + (i*4 + wave)*512);
    }
  };
  auto LOADV = [&](int jb, s16x8* vf) {    // 8 dwordx4 per lane, L2-resident
#pragma unroll
    for (int s = 0; s < 4; ++s) {
      vf[s]   = *(const s16x8*)(Vg + (size_t)l31*SEQ      + jb + (s*2+hi)*8);
      vf[4+s] = *(const s16x8*)(Vg + (size_t)(32+l31)*SEQ + jb + (s*2+hi)*8);
    }
  };

  // one half-tile step: QK^T -> softmax -> PV(vf)
  auto TILE = [&](const u16* Kb, const s16x8* vf) {
    f32x16 s0 = {}, s1 = {};
    __builtin_amdgcn_s_setprio(1);
#pragma unroll
    for (int ks = 0; ks < 4; ++ks) {
      int ch = ((ks*2 + hi) ^ sw) * 8;
      s16x8 k0 = *(const s16x8*)(Kb + l31*64 + ch);
      s16x8 k1 = *(const s16x8*)(Kb + (32 + l31)*64 + ch);
      s0 = mfma32(k0, qf[ks], s0);
      s1 = mfma32(k1, qf[ks], s1);
    }
    __builtin_amdgcn_s_setprio(0);

    float p0[16], p1[16];
#pragma unroll
    for (int i = 0; i < 16; ++i) p0[i] = fexp2(s0[i]);
#pragma unroll
    for (int i = 0; i < 16; ++i) p1[i] = fexp2(s1[i]);
    float s8[8];
#pragma unroll
    for (int i = 0; i < 8; ++i) s8[i] = (p0[i] + p0[i+8]) + (p1[i] + p1[i+8]);
    l_run += ((s8[0]+s8[1]) + (s8[2]+s8[3])) + ((s8[4]+s8[5]) + (s8[6]+s8[7]));

    // P^T B-frags: cvt_pk pairs + permlane32_swap (T12), as verified R2-R4
    s16x8 pf[4];
#pragma unroll
    for (int f = 0; f < 2; ++f) {
      const float* pp = f ? p1 : p0;
      unsigned pk[4][2];
#pragma unroll
      for (int q = 0; q < 4; ++q)
#pragma unroll
        for (int i = 0; i < 2; ++i)
          asm("v_cvt_pk_bf16_f32 %0, %1, %2"
              : "=v"(pk[q][i]) : "v"(pp[4*q+2*i]), "v"(pp[4*q+2*i+1]));
#pragma unroll
      for (int kc = 0; kc < 2; ++kc) {
        union { unsigned u[4]; s16x8 v; } bfu;
#pragma unroll
        for (int i = 0; i < 2; ++i) {
          unsigned x = pk[2*kc][i], y = pk[2*kc+1][i];
          asm("v_permlane32_swap_b32 %0, %1" : "+v"(x), "+v"(y));
          bfu.u[i] = x; bfu.u[2+i] = y;
        }
        pf[2*f+kc] = bfu.v;
      }
    }

    __builtin_amdgcn_s_setprio(1);
#pragma unroll
    for (int s = 0; s < 4; ++s) {
      o0 = mfma32(vf[s],   pf[s], o0);
      o1 = mfma32(vf[4+s], pf[s], o1);
    }
    __builtin_amdgcn_s_setprio(0);
  };

  s16x8 vA[8], vB[8];
  STAGEK(0, 0);                    // issue order: K0(2), K1(2), V0(8)
  STAGEK(64, 1);
  LOADV(0, vA);
  asm volatile("s_waitcnt vmcnt(8)" ::: "memory");  // K0,K1 retired pre-barrier

  const int NT = SEQ/64;           // 32, even
  for (int t = 0; t < NT; t += 2) {
    // ---- tile t (uses vA) ----
    __builtin_amdgcn_s_barrier();
    __builtin_amdgcn_sched_barrier(0);
    if (t + 2 < NT) STAGEK((t+2)*64, (t+2)%3);
    LOADV((t+1)*64, vB);                       // t+1 <= NT-1 always
    TILE(Kt[t%3], vA);
    // ---- tile t+1 (uses vB) ----
    __builtin_amdgcn_s_barrier();
    __builtin_amdgcn_sched_barrier(0);
    if (t + 3 < NT) STAGEK((t+3)*64, (t+3)%3);
    if (t + 2 < NT) LOADV((t+2)*64, vA);
    TILE(Kt[(t+1)%3], vB);
  }

  // epilogue: O^T value r of frag df sits at d = (r&3) + 8*(r>>2) + 4*hi + 32*df
  float l_all = l_run + __shfl_xor(l_run, 32, 64);
  float inv = 1.f / l_all;
  int b = bh >> 4, h = bh & 15;
  u16* dst = Oa + ((size_t)(b*SEQ + q0 + l31))*CDIM + h*HDIM;
#pragma unroll
  for (int df = 0; df < 2; ++df)
#pragma unroll
    for (int q2 = 0; q2 < 4; ++q2) {
      float a0, a1, a2, a3;
      if (df) { a0=o1[4*q2]; a1=o1[4*q2+1]; a2=o1[4*q2+2]; a3=o1[4*q2+3]; }
      else    { a0=o0[4*q2]; a1=o0[4*q2+1]; a2=o0[4*q2+2]; a3=o0[4*q2+3]; }
      a0 *= inv; a1 *= inv; a2 *= inv; a3 *= inv;
      unsigned w0, w1;
      asm("v_cvt_pk_bf16_f32 %0, %1, %2" : "=v"(w0) : "v"(a0), "v"(a1));
      asm("v_cvt_pk_bf16_f32 %0, %1, %2" : "=v"(w1) : "v"(a2), "v"(a3));
      uint2 st; st.x = w0; st.y = w1;
      *(uint2*)(dst + df*32 + q2*8 + hi*4) = st;
    }
}

// ---------------- launch ----------------------------------------------------
extern "C" void kernel_launch(void* const* d_in, const int* in_sizes, int n_in,
                              void* d_out, int out_size, void* d_ws, size_t ws_size,
                              hipStream_t stream)
{
  const float* x      = (const float*)d_in[0];
  const float* qkv_w  = (const float*)d_in[1];
  const float* qnw    = (const float*)d_in[2];
  const float* qnb    = (const float*)d_in[3];
  const float* knw    = (const float*)d_in[4];
  const float* knb    = (const float*)d_in[5];
  const float* proj_w = (const float*)d_in[6];
  const float* proj_b = (const float*)d_in[7];
  float* out = (float*)d_out;

  char* ws = (char*)d_ws;                     // 72 MB used
  u16* xb    = (u16*)(ws);                    //  8 MB  x bf16
  u16* wqkv  = (u16*)(ws + (8ull  << 20));    //  6 MB  qkv_w bf16
  u16* wproj = (u16*)(ws + (14ull << 20));    //  2 MB  proj_w bf16
  u16* qkvb  = (u16*)(ws + (16ull << 20));    // 24 MB  qkv out bf16
  u16* Qsb   = (u16*)(ws + (40ull << 20));    //  8 MB  [B,H,N,D]
  u16* Knb   = (u16*)(ws + (48ull << 20));    //  8 MB  [B,H,N,D]
  u16* Vtb   = (u16*)(ws + (56ull << 20));    //  8 MB  [B,H,D,N]
  u16* Oab   = (u16*)(ws + (64ull << 20));    //  8 MB  attn out [M][C]

  cast_all<<<(XSEG + W1SEG + W2SEG)/256, 256, 0, stream>>>(
      x, qkv_w, proj_w, xb, wqkv, wproj);

  gemm_nt<true, false><<<dim3(MTOT/128, C3/128), 256, 0, stream>>>(
      xb, wqkv, qkvb, nullptr, MTOT, C3, CDIM);

  ln_qk<<<(MTOT*NHEAD)/4, 256, 0, stream>>>(qkvb, qnw, qnb, knw, knb, Qsb, Knb);
  v_transpose<<<dim3(NBATCH*NHEAD, SEQ/64), 256, 0, stream>>>(qkvb, Vtb);

  flash_attn<<<dim3(SEQ/128, NBATCH*NHEAD), 256, 0, stream>>>(Qsb, Knb, Vtb, Oab);

  gemm_nt<false, true><<<dim3(MTOT/128, CDIM/128), 256, 0, stream>>>(
      Oab, wproj, out, proj_b, MTOT, CDIM, CDIM);
}

// Round 6
// 217.418 us; speedup vs baseline: 1.0681x; 1.0681x over previous
//
#include <hip/hip_runtime.h>
#include <cstdint>
#include <cstddef>

// ---------------- problem constants ----------------
#define SEQ     2048
#define NBATCH  2
#define CDIM    1024
#define NHEAD   16
#define HDIM    64
#define MTOT    (NBATCH*SEQ)   // 4096 rows
#define C3      (3*CDIM)       // 3072
#define LOG2E   1.44269504088896340736f
#define QKSCALE (0.125f*LOG2E) // HDIM^-0.5, exp2-domain fold
#define LN_EPS  1e-5f

typedef unsigned short u16;
typedef short s16x8 __attribute__((ext_vector_type(8)));   // 8 bf16 (4 VGPR)
typedef float f32x4  __attribute__((ext_vector_type(4)));
typedef float f32x16 __attribute__((ext_vector_type(16)));

static __device__ __forceinline__ f32x4 mfma16(s16x8 a, s16x8 b, f32x4 c) {
  return __builtin_amdgcn_mfma_f32_16x16x32_bf16(a, b, c, 0, 0, 0);
}
static __device__ __forceinline__ f32x16 mfma32(s16x8 a, s16x8 b, f32x16 c) {
  return __builtin_amdgcn_mfma_f32_32x32x16_bf16(a, b, c, 0, 0, 0);
}
static __device__ __forceinline__ float b2f(u16 v) {
  return __uint_as_float(((unsigned)v) << 16);
}
static __device__ __forceinline__ u16 f2b(float f) {   // RNE fp32->bf16
  unsigned u = __float_as_uint(f);
  u = u + 0x7fffu + ((u >> 16) & 1u);
  return (u16)(u >> 16);
}
// raw v_exp_f32 (2^x). Inputs bounded |x|<=12 here -> no specials.
static __device__ __forceinline__ float fexp2(float x) {
  float r;
  asm("v_exp_f32 %0, %1" : "=v"(r) : "v"(x));
  return r;
}

// async global->LDS, 16B per lane, LDS dst = wave-uniform base + lane*16
#define G2L16(g, l) __builtin_amdgcn_global_load_lds( \
    (__attribute__((address_space(1))) void*)(g),     \
    (__attribute__((address_space(3))) void*)(l), 16, 0, 0)

// ---------------- fused fp32 -> bf16 casts (x, qkv_w, proj_w) ---------------
#define XSEG   (MTOT*CDIM/8)        // 524288 chunks of 8
#define W1SEG  (C3*CDIM/8)          // 393216
#define W2SEG  (CDIM*CDIM/8)        // 131072
__global__ __launch_bounds__(256) void cast_all(
    const float* __restrict__ x, const float* __restrict__ w1,
    const float* __restrict__ w2, u16* __restrict__ xb,
    u16* __restrict__ wqkv, u16* __restrict__ wproj)
{
  int i = blockIdx.x * 256 + threadIdx.x;
  const float* src; u16* dst; int off;
  if (i < XSEG)              { src = x;  dst = xb;    off = i; }
  else if (i < XSEG + W1SEG) { src = w1; dst = wqkv;  off = i - XSEG; }
  else                       { src = w2; dst = wproj; off = i - XSEG - W1SEG; }
  float4 a = ((const float4*)src)[2*off];
  float4 b = ((const float4*)src)[2*off+1];
  union { u16 u[8]; uint4 v; } r;
  r.u[0]=f2b(a.x); r.u[1]=f2b(a.y); r.u[2]=f2b(a.z); r.u[3]=f2b(a.w);
  r.u[4]=f2b(b.x); r.u[5]=f2b(b.y); r.u[6]=f2b(b.z); r.u[7]=f2b(b.w);
  ((uint4*)dst)[off] = r.v;
}

// ---------------- NT GEMM: C[M][N] = A[M][K] * B[N][K]^T  (bf16 MFMA) ------
// m97 structure: 128x128 tile, 4 waves (2x2), BK=64, global_load_lds w=16.
// T2 XOR-swizzle (chunk ^= row&7) via pre-swizzled global source (m173).
// Grid is (Mtiles, Ntiles): linear dispatch round-robins M -> each XCD's
// A-panels stay L2-resident; B streams via L3.  (R5: saved ~15 us vs R4.)
template<bool WRITE_BF16, bool BIAS>
__global__ __launch_bounds__(256) void gemm_nt(
    const u16* __restrict__ A, const u16* __restrict__ Bm,
    void* __restrict__ Cout, const float* __restrict__ bias,
    int M, int Nn, int K)
{
  __shared__ u16 As[128*64];   // [row][64] swizzled, 16KB
  __shared__ u16 Bs[128*64];
  const int tid = threadIdx.x;
  const int wave = tid >> 6, lane = tid & 63;
  const int l15 = lane & 15, l4 = lane >> 4;
  const int m0 = blockIdx.x * 128, n0 = blockIdx.y * 128;
  const int wr = (wave >> 1) * 64, wc = (wave & 1) * 64;
  f32x4 acc[4][4] = {};

  for (int k0 = 0; k0 < K; k0 += 64) {
    if (k0) __syncthreads();                 // prev reads done before restage
#pragma unroll
    for (int i = 0; i < 4; ++i) {            // 4 issues/wave for A and for B
      int ci  = (i*4 + wave)*64 + lane;      // 16B-chunk index 0..1023
      int row = ci >> 3, ch = ci & 7;        // 8 chunks per 128B row
      int chs = ch ^ (row & 7);              // pre-swizzled source
      const u16* ga = A  + (size_t)(m0 + row)*K + k0 + chs*8;
      const u16* gb = Bm + (size_t)(n0 + row)*K + k0 + chs*8;
      G2L16(ga, As + (i*4 + wave)*512);
      G2L16(gb, Bs + (i*4 + wave)*512);
    }
    __syncthreads();                          // barrier drains vmcnt

#pragma unroll
    for (int kk = 0; kk < 2; ++kk) {
      s16x8 af[4], bf[4];
#pragma unroll
      for (int r = 0; r < 4; ++r) {
        int row = wr + r*16 + l15;
        af[r] = *(const s16x8*)(As + row*64 + (((kk*4 + l4) ^ (row & 7))*8));
      }
#pragma unroll
      for (int c = 0; c < 4; ++c) {
        int row = wc + c*16 + l15;
        bf[c] = *(const s16x8*)(Bs + row*64 + (((kk*4 + l4) ^ (row & 7))*8));
      }
#pragma unroll
      for (int r = 0; r < 4; ++r)
#pragma unroll
        for (int c = 0; c < 4; ++c)
          acc[r][c] = mfma16(af[r], bf[c], acc[r][c]);
    }
  }

  // C/D layout: row=(lane>>4)*4+reg, col=lane&15
#pragma unroll
  for (int r = 0; r < 4; ++r)
#pragma unroll
    for (int c = 0; c < 4; ++c) {
      int row = m0 + wr + r*16 + l4*4;
      int col = n0 + wc + c*16 + l15;
#pragma unroll
      for (int q = 0; q < 4; ++q) {
        float v = acc[r][c][q];
        if (BIAS) v += bias[col];
        if (WRITE_BF16) ((u16*)Cout)[(size_t)(row + q)*Nn + col] = f2b(v);
        else           ((float*)Cout)[(size_t)(row + q)*Nn + col] = v;
      }
    }
}

// ---------------- per-head LayerNorm of q,k (wave per (row,head)) ----------
// qkv[m][3072] bf16 -> Qs = LN(q)*QKSCALE (exp2-domain), Kn = LN(k), bf16.
// k-centering is softmax-invariant -> skipped.
__global__ __launch_bounds__(256) void ln_qk(
    const u16* __restrict__ qkv,
    const float* __restrict__ qw, const float* __restrict__ qb,
    const float* __restrict__ kw, const float* __restrict__ kb,
    u16* __restrict__ Qs, u16* __restrict__ Kn)
{
  int gw   = blockIdx.x * 4 + (threadIdx.x >> 6);   // global wave id
  int lane = threadIdx.x & 63;                      // = d
  int m = gw >> 4, h = gw & 15;
  const u16* rowp = qkv + (size_t)m*C3 + h*HDIM + lane;
  int b = m >> 11, n = m & 2047;
  size_t o = ((size_t)(b*NHEAD + h)*SEQ + n)*HDIM + lane;

  float wq = qw[lane], bq = qb[lane], wk = kw[lane], bk = kb[lane];
  float xq = b2f(rowp[0]);
  float xk = b2f(rowp[CDIM]);
  float sq = xq, s2q = xq*xq, sk = xk, s2k = xk*xk;
#pragma unroll
  for (int off = 32; off; off >>= 1) {
    sq += __shfl_xor(sq, off, 64);  s2q += __shfl_xor(s2q, off, 64);
    sk += __shfl_xor(sk, off, 64);  s2k += __shfl_xor(s2k, off, 64);
  }
  float muq = sq*(1.f/64.f), varq = s2q*(1.f/64.f) - muq*muq;
  float muk = sk*(1.f/64.f), vark = s2k*(1.f/64.f) - muk*muk;
  float yq = (xq - muq) * (1.f/sqrtf(varq + LN_EPS)) * wq + bq;
  float yk = (xk - muk) * (1.f/sqrtf(vark + LN_EPS)) * wk + bk;
  Qs[o] = f2b(yq * QKSCALE);
  Kn[o] = f2b(yk);
}

// ---------------- V transpose: qkv v-part -> Vt [B,H,D,N] bf16 -------------
__global__ __launch_bounds__(256) void v_transpose(
    const u16* __restrict__ qkv, u16* __restrict__ Vt)
{
  __shared__ u16 t[64][80];            // +16 pad
  int bh = blockIdx.x, j0 = blockIdx.y * 64;
  int b = bh >> 4, h = bh & 15;
  int tid = threadIdx.x;
  int nl = tid >> 2, ch = tid & 3;
  const u16* src = qkv + (size_t)(b*SEQ + j0 + nl)*C3 + 2*CDIM + h*HDIM + ch*16;
  *(uint4*)&t[nl][ch*16]     = *(const uint4*)src;
  *(uint4*)&t[nl][ch*16 + 8] = *(const uint4*)(src + 8);
  __syncthreads();
  int d = tid >> 2, nc = tid & 3;
  u16 o[16];
#pragma unroll
  for (int i = 0; i < 16; ++i) o[i] = t[nc*16 + i][d];
  u16* dst = Vt + ((size_t)(bh*HDIM + d))*SEQ + j0 + nc*16;
  *(uint4*)dst       = *(uint4*)&o[0];
  *(uint4*)(dst + 8) = *(uint4*)&o[8];
}

// ---------------- flash attention (32x32 MFMA, R3 structure, 2-wave) --------
// R3-proven core (59.7 us at 4 waves): K and V both 2-buf LDS via
// global_load_lds (XOR-swizzled source), ONE __syncthreads per tile.
// R6 change: 128-thread blocks (2 waves), grid (32,32)=1024 -> 4 independent
// blocks/CU instead of 2. Same 8 waves/CU, but barrier groups are decoupled:
// blocks sit at different phases, so setprio(1) around MFMA has cross-block
// arbitration to win (m191 regime) and a barrier drain idles 2 waves not 4.
// Swapped QK^T (S^T = K*Q^T, lane = q-row), no-max exp2 softmax (LN bounds
// |logit| <= 8), P^T via v_cvt_pk_bf16_f32 + v_permlane32_swap_b32.
__global__ __launch_bounds__(128) void flash_attn(
    const u16* __restrict__ Qs, const u16* __restrict__ Kn,
    const u16* __restrict__ Vt, u16* __restrict__ Oa)
{
  __shared__ u16 Kt[2][64*64];     // [kv][d] swizzled, 2x8KB
  __shared__ u16 Vs[2][64*64];     // [d][kv] swizzled, 2x8KB
  const int tid = threadIdx.x, wave = tid >> 6, lane = tid & 63;
  const int l31 = lane & 31, hi = lane >> 5;
  const int bh = blockIdx.y, q0 = blockIdx.x*64 + wave*32;
  const int sw = l31 & 7;

  // Q^T B-fragments: lane holds Q[q0+l31][ks*16 + hi*8 + j], j=0..7
  const u16* Qrow = Qs + ((size_t)bh*SEQ + q0 + l31)*HDIM + hi*8;
  s16x8 qf[4];
#pragma unroll
  for (int ks = 0; ks < 4; ++ks)
    qf[ks] = *(const s16x8*)(Qrow + ks*16);

  f32x16 o0 = {}, o1 = {};
  float l_run = 0.f;

  const u16* Kg = Kn + (size_t)bh*SEQ*HDIM;
  const u16* Vg = Vt + (size_t)bh*HDIM*SEQ;

  // staging: 512 x 16B chunks per K (and V) buffer; 4 issues/wave each
  auto STAGE = [&](int jb, int buf) {
#pragma unroll
    for (int i = 0; i < 4; ++i) {
      int ci = (i*2 + wave)*64 + lane;
      int row = ci >> 3, ch = ci & 7;
      int chs = ch ^ (row & 7);               // pre-swizzled source
      G2L16(Kg + (size_t)(jb + row)*HDIM + chs*8, Kt[buf] + (i*2 + wave)*512);
      G2L16(Vg + (size_t)row*SEQ + jb + chs*8,    Vs[buf] + (i*2 + wave)*512);
    }
  };

  STAGE(0, 0);
  __syncthreads();

  const int NT = SEQ/64;           // 32
  for (int t = 0; t < NT; ++t) {
    const int buf = t & 1;
    if (t + 1 < NT) STAGE((t+1)*64, buf ^ 1);   // prefetch next tile
    const u16* Kb = Kt[buf];
    const u16* Vb = Vs[buf];

    // S^T = K * Q^T : two 32-kv fragments (rows kv, cols q=l31)
    f32x16 s0 = {}, s1 = {};
    __builtin_amdgcn_s_setprio(1);
#pragma unroll
    for (int ks = 0; ks < 4; ++ks) {
      int ch = ((ks*2 + hi) ^ sw) * 8;
      s16x8 k0 = *(const s16x8*)(Kb + l31*64 + ch);
      s16x8 k1 = *(const s16x8*)(Kb + (32 + l31)*64 + ch);
      s0 = mfma32(k0, qf[ks], s0);
      s1 = mfma32(k1, qf[ks], s1);
    }
    __builtin_amdgcn_s_setprio(0);

    // P = exp2(S), l += tree-sum  (no max shift; bounded by LN)
    float p0[16], p1[16];
#pragma unroll
    for (int i = 0; i < 16; ++i) p0[i] = fexp2(s0[i]);
#pragma unroll
    for (int i = 0; i < 16; ++i) p1[i] = fexp2(s1[i]);
    float s8[8];
#pragma unroll
    for (int i = 0; i < 8; ++i) s8[i] = (p0[i] + p0[i+8]) + (p1[i] + p1[i+8]);
    l_run += ((s8[0]+s8[1]) + (s8[2]+s8[3])) + ((s8[4]+s8[5]) + (s8[6]+s8[7]));

    // P^T B-frags: cvt_pk pairs + permlane32_swap (T12), as verified R2-R5
    s16x8 pf[4];
#pragma unroll
    for (int f = 0; f < 2; ++f) {
      const float* pp = f ? p1 : p0;
      unsigned pk[4][2];
#pragma unroll
      for (int q = 0; q < 4; ++q)
#pragma unroll
        for (int i = 0; i < 2; ++i)
          asm("v_cvt_pk_bf16_f32 %0, %1, %2"
              : "=v"(pk[q][i]) : "v"(pp[4*q+2*i]), "v"(pp[4*q+2*i+1]));
#pragma unroll
      for (int kc = 0; kc < 2; ++kc) {
        union { unsigned u[4]; s16x8 v; } bfu;
#pragma unroll
        for (int i = 0; i < 2; ++i) {
          unsigned x = pk[2*kc][i], y = pk[2*kc+1][i];
          asm("v_permlane32_swap_b32 %0, %1" : "+v"(x), "+v"(y));
          bfu.u[i] = x; bfu.u[2+i] = y;
        }
        pf[2*f+kc] = bfu.v;
      }
    }

    // O^T += V^T * P^T   (rows d, cols q=l31)
    __builtin_amdgcn_s_setprio(1);
#pragma unroll
    for (int s = 0; s < 4; ++s) {
      int ch = ((s*2 + hi) ^ sw) * 8;
      s16x8 v0 = *(const s16x8*)(Vb + l31*64 + ch);
      s16x8 v1 = *(const s16x8*)(Vb + (32 + l31)*64 + ch);
      o0 = mfma32(v0, pf[s], o0);
      o1 = mfma32(v1, pf[s], o1);
    }
    __builtin_amdgcn_s_setprio(0);
    __syncthreads();           // prefetch landed; next iter reads buf^1
  }

  // epilogue: O^T value r of frag df sits at d = (r&3) + 8*(r>>2) + 4*hi + 32*df
  float l_all = l_run + __shfl_xor(l_run, 32, 64);
  float inv = 1.f / l_all;
  int b = bh >> 4, h = bh & 15;
  u16* dst = Oa + ((size_t)(b*SEQ + q0 + l31))*CDIM + h*HDIM;
#pragma unroll
  for (int df = 0; df < 2; ++df)
#pragma unroll
    for (int q2 = 0; q2 < 4; ++q2) {
      float a0, a1, a2, a3;
      if (df) { a0=o1[4*q2]; a1=o1[4*q2+1]; a2=o1[4*q2+2]; a3=o1[4*q2+3]; }
      else    { a0=o0[4*q2]; a1=o0[4*q2+1]; a2=o0[4*q2+2]; a3=o0[4*q2+3]; }
      a0 *= inv; a1 *= inv; a2 *= inv; a3 *= inv;
      unsigned w0, w1;
      asm("v_cvt_pk_bf16_f32 %0, %1, %2" : "=v"(w0) : "v"(a0), "v"(a1));
      asm("v_cvt_pk_bf16_f32 %0, %1, %2" : "=v"(w1) : "v"(a2), "v"(a3));
      uint2 st; st.x = w0; st.y = w1;
      *(uint2*)(dst + df*32 + q2*8 + hi*4) = st;
    }
}

// ---------------- launch ----------------------------------------------------
extern "C" void kernel_launch(void* const* d_in, const int* in_sizes, int n_in,
                              void* d_out, int out_size, void* d_ws, size_t ws_size,
                              hipStream_t stream)
{
  const float* x      = (const float*)d_in[0];
  const float* qkv_w  = (const float*)d_in[1];
  const float* qnw    = (const float*)d_in[2];
  const float* qnb    = (const float*)d_in[3];
  const float* knw    = (const float*)d_in[4];
  const float* knb    = (const float*)d_in[5];
  const float* proj_w = (const float*)d_in[6];
  const float* proj_b = (const float*)d_in[7];
  float* out = (float*)d_out;

  char* ws = (char*)d_ws;                     // 72 MB used
  u16* xb    = (u16*)(ws);                    //  8 MB  x bf16
  u16* wqkv  = (u16*)(ws + (8ull  << 20));    //  6 MB  qkv_w bf16
  u16* wproj = (u16*)(ws + (14ull << 20));    //  2 MB  proj_w bf16
  u16* qkvb  = (u16*)(ws + (16ull << 20));    // 24 MB  qkv out bf16
  u16* Qsb   = (u16*)(ws + (40ull << 20));    //  8 MB  [B,H,N,D]
  u16* Knb   = (u16*)(ws + (48ull << 20));    //  8 MB  [B,H,N,D]
  u16* Vtb   = (u16*)(ws + (56ull << 20));    //  8 MB  [B,H,D,N]
  u16* Oab   = (u16*)(ws + (64ull << 20));    //  8 MB  attn out [M][C]

  cast_all<<<(XSEG + W1SEG + W2SEG)/256, 256, 0, stream>>>(
      x, qkv_w, proj_w, xb, wqkv, wproj);

  gemm_nt<true, false><<<dim3(MTOT/128, C3/128), 256, 0, stream>>>(
      xb, wqkv, qkvb, nullptr, MTOT, C3, CDIM);

  ln_qk<<<(MTOT*NHEAD)/4, 256, 0, stream>>>(qkvb, qnw, qnb, knw, knb, Qsb, Knb);
  v_transpose<<<dim3(NBATCH*NHEAD, SEQ/64), 256, 0, stream>>>(qkvb, Vtb);

  flash_attn<<<dim3(SEQ/64, NBATCH*NHEAD), 128, 0, stream>>>(Qsb, Knb, Vtb, Oab);

  gemm_nt<false, true><<<dim3(MTOT/128, CDIM/128), 256, 0, stream>>>(
      Oab, wproj, out, proj_b, MTOT, CDIM, CDIM);
}

// Round 7
// 198.477 us; speedup vs baseline: 1.1701x; 1.0954x over previous
//
#include <hip/hip_runtime.h>
#include <cstdint>
#include <cstddef>

// ---------------- problem constants ----------------
#define SEQ     2048
#define NBATCH  2
#define CDIM    1024
#define NHEAD   16
#define HDIM    64
#define MTOT    (NBATCH*SEQ)   // 4096 rows
#define C3      (3*CDIM)       // 3072
#define LOG2E   1.44269504088896340736f
#define QKSCALE (0.125f*LOG2E) // HDIM^-0.5, exp2-domain fold
#define LN_EPS  1e-5f

typedef unsigned short u16;
typedef short s16x8 __attribute__((ext_vector_type(8)));   // 8 bf16 (4 VGPR)
typedef float f32x4  __attribute__((ext_vector_type(4)));
typedef float f32x16 __attribute__((ext_vector_type(16)));

static __device__ __forceinline__ f32x4 mfma16(s16x8 a, s16x8 b, f32x4 c) {
  return __builtin_amdgcn_mfma_f32_16x16x32_bf16(a, b, c, 0, 0, 0);
}
static __device__ __forceinline__ f32x16 mfma32(s16x8 a, s16x8 b, f32x16 c) {
  return __builtin_amdgcn_mfma_f32_32x32x16_bf16(a, b, c, 0, 0, 0);
}
static __device__ __forceinline__ float b2f(u16 v) {
  return __uint_as_float(((unsigned)v) << 16);
}
static __device__ __forceinline__ u16 f2b(float f) {   // RNE fp32->bf16
  unsigned u = __float_as_uint(f);
  u = u + 0x7fffu + ((u >> 16) & 1u);
  return (u16)(u >> 16);
}
// raw v_exp_f32 (2^x). Inputs bounded |x|<=12 here -> no specials.
static __device__ __forceinline__ float fexp2(float x) {
  float r;
  asm("v_exp_f32 %0, %1" : "=v"(r) : "v"(x));
  return r;
}

// async global->LDS, 16B per lane, LDS dst = wave-uniform base + lane*16
#define G2L16(g, l) __builtin_amdgcn_global_load_lds( \
    (__attribute__((address_space(1))) void*)(g),     \
    (__attribute__((address_space(3))) void*)(l), 16, 0, 0)

// ---------------- fused fp32 -> bf16 casts (x, qkv_w, proj_w) ---------------
#define XSEG   (MTOT*CDIM/8)        // 524288 chunks of 8
#define W1SEG  (C3*CDIM/8)          // 393216
#define W2SEG  (CDIM*CDIM/8)        // 131072
__global__ __launch_bounds__(256) void cast_all(
    const float* __restrict__ x, const float* __restrict__ w1,
    const float* __restrict__ w2, u16* __restrict__ xb,
    u16* __restrict__ wqkv, u16* __restrict__ wproj)
{
  int i = blockIdx.x * 256 + threadIdx.x;
  const float* src; u16* dst; int off;
  if (i < XSEG)              { src = x;  dst = xb;    off = i; }
  else if (i < XSEG + W1SEG) { src = w1; dst = wqkv;  off = i - XSEG; }
  else                       { src = w2; dst = wproj; off = i - XSEG - W1SEG; }
  float4 a = ((const float4*)src)[2*off];
  float4 b = ((const float4*)src)[2*off+1];
  union { u16 u[8]; uint4 v; } r;
  r.u[0]=f2b(a.x); r.u[1]=f2b(a.y); r.u[2]=f2b(a.z); r.u[3]=f2b(a.w);
  r.u[4]=f2b(b.x); r.u[5]=f2b(b.y); r.u[6]=f2b(b.z); r.u[7]=f2b(b.w);
  ((uint4*)dst)[off] = r.v;
}

// ---------------- NT GEMM: C[M][N] = A[M][K] * B[N][K]^T  (bf16 MFMA) ------
// m97 structure: 128x128 tile, 4 waves (2x2), BK=64, global_load_lds w=16.
// T2 XOR-swizzle (chunk ^= row&7) via pre-swizzled global source (m173).
// Grid is (Mtiles, Ntiles): linear dispatch round-robins M -> each XCD's
// A-panels stay L2-resident; B streams via L3.  (R5: saved ~15 us vs R4.)
template<bool WRITE_BF16, bool BIAS>
__global__ __launch_bounds__(256) void gemm_nt(
    const u16* __restrict__ A, const u16* __restrict__ Bm,
    void* __restrict__ Cout, const float* __restrict__ bias,
    int M, int Nn, int K)
{
  __shared__ u16 As[128*64];   // [row][64] swizzled, 16KB
  __shared__ u16 Bs[128*64];
  const int tid = threadIdx.x;
  const int wave = tid >> 6, lane = tid & 63;
  const int l15 = lane & 15, l4 = lane >> 4;
  const int m0 = blockIdx.x * 128, n0 = blockIdx.y * 128;
  const int wr = (wave >> 1) * 64, wc = (wave & 1) * 64;
  f32x4 acc[4][4] = {};

  for (int k0 = 0; k0 < K; k0 += 64) {
    if (k0) __syncthreads();                 // prev reads done before restage
#pragma unroll
    for (int i = 0; i < 4; ++i) {            // 4 issues/wave for A and for B
      int ci  = (i*4 + wave)*64 + lane;      // 16B-chunk index 0..1023
      int row = ci >> 3, ch = ci & 7;        // 8 chunks per 128B row
      int chs = ch ^ (row & 7);              // pre-swizzled source
      const u16* ga = A  + (size_t)(m0 + row)*K + k0 + chs*8;
      const u16* gb = Bm + (size_t)(n0 + row)*K + k0 + chs*8;
      G2L16(ga, As + (i*4 + wave)*512);
      G2L16(gb, Bs + (i*4 + wave)*512);
    }
    __syncthreads();                          // barrier drains vmcnt

#pragma unroll
    for (int kk = 0; kk < 2; ++kk) {
      s16x8 af[4], bf[4];
#pragma unroll
      for (int r = 0; r < 4; ++r) {
        int row = wr + r*16 + l15;
        af[r] = *(const s16x8*)(As + row*64 + (((kk*4 + l4) ^ (row & 7))*8));
      }
#pragma unroll
      for (int c = 0; c < 4; ++c) {
        int row = wc + c*16 + l15;
        bf[c] = *(const s16x8*)(Bs + row*64 + (((kk*4 + l4) ^ (row & 7))*8));
      }
#pragma unroll
      for (int r = 0; r < 4; ++r)
#pragma unroll
        for (int c = 0; c < 4; ++c)
          acc[r][c] = mfma16(af[r], bf[c], acc[r][c]);
    }
  }

  // C/D layout: row=(lane>>4)*4+reg, col=lane&15
#pragma unroll
  for (int r = 0; r < 4; ++r)
#pragma unroll
    for (int c = 0; c < 4; ++c) {
      int row = m0 + wr + r*16 + l4*4;
      int col = n0 + wc + c*16 + l15;
#pragma unroll
      for (int q = 0; q < 4; ++q) {
        float v = acc[r][c][q];
        if (BIAS) v += bias[col];
        if (WRITE_BF16) ((u16*)Cout)[(size_t)(row + q)*Nn + col] = f2b(v);
        else           ((float*)Cout)[(size_t)(row + q)*Nn + col] = v;
      }
    }
}

// ---------------- per-head LayerNorm of q,k (vectorized short8) -------------
// Block = 2 rows; wave = (row, q|k); lane covers 8 d of head (lane>>3)+8c.
// 16B loads/stores, 3-level shfl reduce within 8-lane head groups.
// k-centering is softmax-invariant -> skipped; Q pre-scaled to exp2 domain.
__global__ __launch_bounds__(256) void ln_qk(
    const u16* __restrict__ qkv,
    const float* __restrict__ qw, const float* __restrict__ qb,
    const float* __restrict__ kw, const float* __restrict__ kb,
    u16* __restrict__ Qs, u16* __restrict__ Kn)
{
  const int tid = threadIdx.x, wave = tid >> 6, lane = tid & 63;
  const int m = blockIdx.x*2 + (wave >> 1);      // row
  const int part = wave & 1;                     // 0=q, 1=k
  const int b = m >> 11, n = m & 2047;
  const float* wv = part ? kw : qw;
  const float* bv = part ? kb : qb;
  u16* dst = part ? Kn : Qs;
  const float scale = part ? 1.f : QKSCALE;
  const u16* base = qkv + (size_t)m*C3 + part*CDIM;
  const int d0 = (lane & 7) * 8;
  float wl[8], bl[8];
#pragma unroll
  for (int j = 0; j < 8; ++j) { wl[j] = wv[d0+j]*scale; bl[j] = bv[d0+j]*scale; }
#pragma unroll
  for (int c = 0; c < 2; ++c) {
    int h = c*8 + (lane >> 3);
    s16x8 v = *(const s16x8*)(base + c*512 + lane*8);
    float f[8]; float s = 0.f, s2 = 0.f;
#pragma unroll
    for (int j = 0; j < 8; ++j) {
      f[j] = b2f((u16)v[j]); s += f[j]; s2 += f[j]*f[j];
    }
#pragma unroll
    for (int off = 1; off < 8; off <<= 1) {
      s += __shfl_xor(s, off, 64); s2 += __shfl_xor(s2, off, 64);
    }
    float mu = s*(1.f/64.f);
    float rs = rsqrtf(s2*(1.f/64.f) - mu*mu + LN_EPS);
    union { u16 u[8]; uint4 q; } r;
#pragma unroll
    for (int j = 0; j < 8; ++j)
      r.u[j] = f2b((f[j]-mu)*rs*wl[j] + bl[j]);
    *(uint4*)(dst + ((size_t)(b*NHEAD+h)*SEQ + n)*HDIM + d0) = r.q;
  }
}

// ---------------- V transpose: qkv v-part -> Vt [B,H,D,N] bf16 -------------
__global__ __launch_bounds__(256) void v_transpose(
    const u16* __restrict__ qkv, u16* __restrict__ Vt)
{
  __shared__ u16 t[64][80];            // +16 pad
  int bh = blockIdx.x, j0 = blockIdx.y * 64;
  int b = bh >> 4, h = bh & 15;
  int tid = threadIdx.x;
  int nl = tid >> 2, ch = tid & 3;
  const u16* src = qkv + (size_t)(b*SEQ + j0 + nl)*C3 + 2*CDIM + h*HDIM + ch*16;
  *(uint4*)&t[nl][ch*16]     = *(const uint4*)src;
  *(uint4*)&t[nl][ch*16 + 8] = *(const uint4*)(src + 8);
  __syncthreads();
  int d = tid >> 2, nc = tid & 3;
  u16 o[16];
#pragma unroll
  for (int i = 0; i < 16; ++i) o[i] = t[nc*16 + i][d];
  u16* dst = Vt + ((size_t)(bh*HDIM + d))*SEQ + j0 + nc*16;
  *(uint4*)dst       = *(uint4*)&o[0];
  *(uint4*)(dst + 8) = *(uint4*)&o[8];
}

// ---------------- flash attention (R3 structure + XCD chunked swizzle) ------
// 4 waves x QBLK=32 q-rows = 128 q/block; KV tiles of 64; grid (16,32)=512.
// R5-proven chunked swizzle: XCD x owns bh [4x,4x+4) -> 2 MB KV L2-resident
// (R5 measured FETCH 69.7 -> 12.3 MB), so the per-tile barrier drain waits on
// ~250-cyc L2 hits, not ~900-cyc HBM misses, and is covered by the previous
// tile's compute phase.
// R3-proven core (59.7 us): K and V both 2-buf LDS via global_load_lds
// (XOR-swizzled source), ONE __syncthreads per tile, setprio on MFMA.
// Swapped QK^T (S^T = K*Q^T, lane = q-row), no-max exp2 softmax (LN bounds
// |logit| <= 8), P^T via v_cvt_pk_bf16_f32 + v_permlane32_swap_b32.
__global__ __launch_bounds__(256) void flash_attn(
    const u16* __restrict__ Qs, const u16* __restrict__ Kn,
    const u16* __restrict__ Vt, u16* __restrict__ Oa)
{
  __shared__ u16 Kt[2][64*64];     // [kv][d] swizzled, 2x8KB
  __shared__ u16 Vs[2][64*64];     // [d][kv] swizzled, 2x8KB
  const int tid = threadIdx.x, wave = tid >> 6, lane = tid & 63;
  const int l31 = lane & 31, hi = lane >> 5;
  const int bid0 = blockIdx.x + blockIdx.y*16;     // 512 blocks
  const int nid  = (bid0 & 7)*64 + (bid0 >> 3);    // chunked XCD swizzle
  const int bh   = nid >> 4;
  const int q0   = (nid & 15)*128 + wave*32;
  const int sw = l31 & 7;

  // Q^T B-fragments: lane holds Q[q0+l31][ks*16 + hi*8 + j], j=0..7
  const u16* Qrow = Qs + ((size_t)bh*SEQ + q0 + l31)*HDIM + hi*8;
  s16x8 qf[4];
#pragma unroll
  for (int ks = 0; ks < 4; ++ks)
    qf[ks] = *(const s16x8*)(Qrow + ks*16);

  f32x16 o0 = {}, o1 = {};
  float l_run = 0.f;

  const u16* Kg = Kn + (size_t)bh*SEQ*HDIM;
  const u16* Vg = Vt + (size_t)bh*HDIM*SEQ;

  // staging: 512 x 16B chunks per K (and V) buffer; 2 issues/wave each
  auto STAGE = [&](int jb, int buf) {
#pragma unroll
    for (int i = 0; i < 2; ++i) {
      int ci = (i*4 + wave)*64 + lane;
      int row = ci >> 3, ch = ci & 7;
      int chs = ch ^ (row & 7);               // pre-swizzled source
      G2L16(Kg + (size_t)(jb + row)*HDIM + chs*8, Kt[buf] + (i*4 + wave)*512);
      G2L16(Vg + (size_t)row*SEQ + jb + chs*8,    Vs[buf] + (i*4 + wave)*512);
    }
  };

  STAGE(0, 0);
  __syncthreads();

  const int NT = SEQ/64;           // 32
  for (int t = 0; t < NT; ++t) {
    const int buf = t & 1;
    if (t + 1 < NT) STAGE((t+1)*64, buf ^ 1);   // prefetch next tile
    const u16* Kb = Kt[buf];
    const u16* Vb = Vs[buf];

    // S^T = K * Q^T : two 32-kv fragments (rows kv, cols q=l31)
    f32x16 s0 = {}, s1 = {};
    __builtin_amdgcn_s_setprio(1);
#pragma unroll
    for (int ks = 0; ks < 4; ++ks) {
      int ch = ((ks*2 + hi) ^ sw) * 8;
      s16x8 k0 = *(const s16x8*)(Kb + l31*64 + ch);
      s16x8 k1 = *(const s16x8*)(Kb + (32 + l31)*64 + ch);
      s0 = mfma32(k0, qf[ks], s0);
      s1 = mfma32(k1, qf[ks], s1);
    }
    __builtin_amdgcn_s_setprio(0);

    // P = exp2(S), l += tree-sum  (no max shift; bounded by LN)
    float p0[16], p1[16];
#pragma unroll
    for (int i = 0; i < 16; ++i) p0[i] = fexp2(s0[i]);
#pragma unroll
    for (int i = 0; i < 16; ++i) p1[i] = fexp2(s1[i]);
    float s8[8];
#pragma unroll
    for (int i = 0; i < 8; ++i) s8[i] = (p0[i] + p0[i+8]) + (p1[i] + p1[i+8]);
    l_run += ((s8[0]+s8[1]) + (s8[2]+s8[3])) + ((s8[4]+s8[5]) + (s8[6]+s8[7]));

    // P^T B-frags: cvt_pk pairs + permlane32_swap (T12), as verified R2-R6
    s16x8 pf[4];
#pragma unroll
    for (int f = 0; f < 2; ++f) {
      const float* pp = f ? p1 : p0;
      unsigned pk[4][2];
#pragma unroll
      for (int q = 0; q < 4; ++q)
#pragma unroll
        for (int i = 0; i < 2; ++i)
          asm("v_cvt_pk_bf16_f32 %0, %1, %2"
              : "=v"(pk[q][i]) : "v"(pp[4*q+2*i]), "v"(pp[4*q+2*i+1]));
#pragma unroll
      for (int kc = 0; kc < 2; ++kc) {
        union { unsigned u[4]; s16x8 v; } bfu;
#pragma unroll
        for (int i = 0; i < 2; ++i) {
          unsigned x = pk[2*kc][i], y = pk[2*kc+1][i];
          asm("v_permlane32_swap_b32 %0, %1" : "+v"(x), "+v"(y));
          bfu.u[i] = x; bfu.u[2+i] = y;
        }
        pf[2*f+kc] = bfu.v;
      }
    }

    // O^T += V^T * P^T   (rows d, cols q=l31)
    __builtin_amdgcn_s_setprio(1);
#pragma unroll
    for (int s = 0; s < 4; ++s) {
      int ch = ((s*2 + hi) ^ sw) * 8;
      s16x8 v0 = *(const s16x8*)(Vb + l31*64 + ch);
      s16x8 v1 = *(const s16x8*)(Vb + (32 + l31)*64 + ch);
      o0 = mfma32(v0, pf[s], o0);
      o1 = mfma32(v1, pf[s], o1);
    }
    __builtin_amdgcn_s_setprio(0);
    __syncthreads();           // prefetch landed; next iter reads buf^1
  }

  // epilogue: O^T value r of frag df sits at d = (r&3) + 8*(r>>2) + 4*hi + 32*df
  float l_all = l_run + __shfl_xor(l_run, 32, 64);
  float inv = 1.f / l_all;
  int b = bh >> 4, h = bh & 15;
  u16* dst = Oa + ((size_t)(b*SEQ + q0 + l31))*CDIM + h*HDIM;
#pragma unroll
  for (int df = 0; df < 2; ++df)
#pragma unroll
    for (int q2 = 0; q2 < 4; ++q2) {
      float a0, a1, a2, a3;
      if (df) { a0=o1[4*q2]; a1=o1[4*q2+1]; a2=o1[4*q2+2]; a3=o1[4*q2+3]; }
      else    { a0=o0[4*q2]; a1=o0[4*q2+1]; a2=o0[4*q2+2]; a3=o0[4*q2+3]; }
      a0 *= inv; a1 *= inv; a2 *= inv; a3 *= inv;
      unsigned w0, w1;
      asm("v_cvt_pk_bf16_f32 %0, %1, %2" : "=v"(w0) : "v"(a0), "v"(a1));
      asm("v_cvt_pk_bf16_f32 %0, %1, %2" : "=v"(w1) : "v"(a2), "v"(a3));
      uint2 st; st.x = w0; st.y = w1;
      *(uint2*)(dst + df*32 + q2*8 + hi*4) = st;
    }
}

// ---------------- launch ----------------------------------------------------
extern "C" void kernel_launch(void* const* d_in, const int* in_sizes, int n_in,
                              void* d_out, int out_size, void* d_ws, size_t ws_size,
                              hipStream_t stream)
{
  const float* x      = (const float*)d_in[0];
  const float* qkv_w  = (const float*)d_in[1];
  const float* qnw    = (const float*)d_in[2];
  const float* qnb    = (const float*)d_in[3];
  const float* knw    = (const float*)d_in[4];
  const float* knb    = (const float*)d_in[5];
  const float* proj_w = (const float*)d_in[6];
  const float* proj_b = (const float*)d_in[7];
  float* out = (float*)d_out;

  char* ws = (char*)d_ws;                     // 72 MB used
  u16* xb    = (u16*)(ws);                    //  8 MB  x bf16
  u16* wqkv  = (u16*)(ws + (8ull  << 20));    //  6 MB  qkv_w bf16
  u16* wproj = (u16*)(ws + (14ull << 20));    //  2 MB  proj_w bf16
  u16* qkvb  = (u16*)(ws + (16ull << 20));    // 24 MB  qkv out bf16
  u16* Qsb   = (u16*)(ws + (40ull << 20));    //  8 MB  [B,H,N,D]
  u16* Knb   = (u16*)(ws + (48ull << 20));    //  8 MB  [B,H,N,D]
  u16* Vtb   = (u16*)(ws + (56ull << 20));    //  8 MB  [B,H,D,N]
  u16* Oab   = (u16*)(ws + (64ull << 20));    //  8 MB  attn out [M][C]

  cast_all<<<(XSEG + W1SEG + W2SEG)/256, 256, 0, stream>>>(
      x, qkv_w, proj_w, xb, wqkv, wproj);

  gemm_nt<true, false><<<dim3(MTOT/128, C3/128), 256, 0, stream>>>(
      xb, wqkv, qkvb, nullptr, MTOT, C3, CDIM);

  ln_qk<<<MTOT/2, 256, 0, stream>>>(qkvb, qnw, qnb, knw, knb, Qsb, Knb);
  v_transpose<<<dim3(NBATCH*NHEAD, SEQ/64), 256, 0, stream>>>(qkvb, Vtb);

  flash_attn<<<dim3(SEQ/128, NBATCH*NHEAD), 256, 0, stream>>>(Qsb, Knb, Vtb, Oab);

  gemm_nt<false, true><<<dim3(MTOT/128, CDIM/128), 256, 0, stream>>>(
      Oab, wproj, out, proj_b, MTOT, CDIM, CDIM);
}

// Round 8
// 192.767 us; speedup vs baseline: 1.2047x; 1.0296x over previous
//
#include <hip/hip_runtime.h>
#include <cstdint>
#include <cstddef>

// ---------------- problem constants ----------------
#define SEQ     2048
#define NBATCH  2
#define CDIM    1024
#define NHEAD   16
#define HDIM    64
#define MTOT    (NBATCH*SEQ)   // 4096 rows
#define C3      (3*CDIM)       // 3072
#define LOG2E   1.44269504088896340736f
#define QKSCALE (0.125f*LOG2E) // HDIM^-0.5, exp2-domain fold
#define LN_EPS  1e-5f

typedef unsigned short u16;
typedef short s16x8 __attribute__((ext_vector_type(8)));   // 8 bf16 (4 VGPR)
typedef float f32x4  __attribute__((ext_vector_type(4)));
typedef float f32x16 __attribute__((ext_vector_type(16)));

static __device__ __forceinline__ f32x4 mfma16(s16x8 a, s16x8 b, f32x4 c) {
  return __builtin_amdgcn_mfma_f32_16x16x32_bf16(a, b, c, 0, 0, 0);
}
static __device__ __forceinline__ f32x16 mfma32(s16x8 a, s16x8 b, f32x16 c) {
  return __builtin_amdgcn_mfma_f32_32x32x16_bf16(a, b, c, 0, 0, 0);
}
static __device__ __forceinline__ float b2f(u16 v) {
  return __uint_as_float(((unsigned)v) << 16);
}
static __device__ __forceinline__ u16 f2b(float f) {   // RNE fp32->bf16
  unsigned u = __float_as_uint(f);
  u = u + 0x7fffu + ((u >> 16) & 1u);
  return (u16)(u >> 16);
}
// raw v_exp_f32 (2^x). Inputs bounded |x|<=12 here -> no specials.
static __device__ __forceinline__ float fexp2(float x) {
  float r;
  asm("v_exp_f32 %0, %1" : "=v"(r) : "v"(x));
  return r;
}

// async global->LDS, 16B per lane, LDS dst = wave-uniform base + lane*16
#define G2L16(g, l) __builtin_amdgcn_global_load_lds( \
    (__attribute__((address_space(1))) void*)(g),     \
    (__attribute__((address_space(3))) void*)(l), 16, 0, 0)

// ---------------- fused fp32 -> bf16 casts (x, qkv_w, proj_w) ---------------
#define XSEG   (MTOT*CDIM/8)        // 524288 chunks of 8
#define W1SEG  (C3*CDIM/8)          // 393216
#define W2SEG  (CDIM*CDIM/8)        // 131072
__global__ __launch_bounds__(256) void cast_all(
    const float* __restrict__ x, const float* __restrict__ w1,
    const float* __restrict__ w2, u16* __restrict__ xb,
    u16* __restrict__ wqkv, u16* __restrict__ wproj)
{
  int i = blockIdx.x * 256 + threadIdx.x;
  const float* src; u16* dst; int off;
  if (i < XSEG)              { src = x;  dst = xb;    off = i; }
  else if (i < XSEG + W1SEG) { src = w1; dst = wqkv;  off = i - XSEG; }
  else                       { src = w2; dst = wproj; off = i - XSEG - W1SEG; }
  float4 a = ((const float4*)src)[2*off];
  float4 b = ((const float4*)src)[2*off+1];
  union { u16 u[8]; uint4 v; } r;
  r.u[0]=f2b(a.x); r.u[1]=f2b(a.y); r.u[2]=f2b(a.z); r.u[3]=f2b(a.w);
  r.u[4]=f2b(b.x); r.u[5]=f2b(b.y); r.u[6]=f2b(b.z); r.u[7]=f2b(b.w);
  ((uint4*)dst)[off] = r.v;
}

// ---------------- NT GEMM: C[M][N] = A[M][K] * B[N][K]^T  (bf16 MFMA) ------
// m97 structure: 128x128 tile, 4 waves (2x2), BK=64, global_load_lds w=16.
// T2 XOR-swizzle (chunk ^= row&7) via pre-swizzled global source (m173).
// Grid is (Mtiles, Ntiles): linear dispatch round-robins M -> each XCD's
// A-panels stay L2-resident; B streams via L3.  (R5: saved ~15 us vs R4.)
template<bool WRITE_BF16, bool BIAS>
__global__ __launch_bounds__(256) void gemm_nt(
    const u16* __restrict__ A, const u16* __restrict__ Bm,
    void* __restrict__ Cout, const float* __restrict__ bias,
    int M, int Nn, int K)
{
  __shared__ u16 As[128*64];   // [row][64] swizzled, 16KB
  __shared__ u16 Bs[128*64];
  const int tid = threadIdx.x;
  const int wave = tid >> 6, lane = tid & 63;
  const int l15 = lane & 15, l4 = lane >> 4;
  const int m0 = blockIdx.x * 128, n0 = blockIdx.y * 128;
  const int wr = (wave >> 1) * 64, wc = (wave & 1) * 64;
  f32x4 acc[4][4] = {};

  for (int k0 = 0; k0 < K; k0 += 64) {
    if (k0) __syncthreads();                 // prev reads done before restage
#pragma unroll
    for (int i = 0; i < 4; ++i) {            // 4 issues/wave for A and for B
      int ci  = (i*4 + wave)*64 + lane;      // 16B-chunk index 0..1023
      int row = ci >> 3, ch = ci & 7;        // 8 chunks per 128B row
      int chs = ch ^ (row & 7);              // pre-swizzled source
      const u16* ga = A  + (size_t)(m0 + row)*K + k0 + chs*8;
      const u16* gb = Bm + (size_t)(n0 + row)*K + k0 + chs*8;
      G2L16(ga, As + (i*4 + wave)*512);
      G2L16(gb, Bs + (i*4 + wave)*512);
    }
    __syncthreads();                          // barrier drains vmcnt

#pragma unroll
    for (int kk = 0; kk < 2; ++kk) {
      s16x8 af[4], bf[4];
#pragma unroll
      for (int r = 0; r < 4; ++r) {
        int row = wr + r*16 + l15;
        af[r] = *(const s16x8*)(As + row*64 + (((kk*4 + l4) ^ (row & 7))*8));
      }
#pragma unroll
      for (int c = 0; c < 4; ++c) {
        int row = wc + c*16 + l15;
        bf[c] = *(const s16x8*)(Bs + row*64 + (((kk*4 + l4) ^ (row & 7))*8));
      }
#pragma unroll
      for (int r = 0; r < 4; ++r)
#pragma unroll
        for (int c = 0; c < 4; ++c)
          acc[r][c] = mfma16(af[r], bf[c], acc[r][c]);
    }
  }

  // C/D layout: row=(lane>>4)*4+reg, col=lane&15
#pragma unroll
  for (int r = 0; r < 4; ++r)
#pragma unroll
    for (int c = 0; c < 4; ++c) {
      int row = m0 + wr + r*16 + l4*4;
      int col = n0 + wc + c*16 + l15;
#pragma unroll
      for (int q = 0; q < 4; ++q) {
        float v = acc[r][c][q];
        if (BIAS) v += bias[col];
        if (WRITE_BF16) ((u16*)Cout)[(size_t)(row + q)*Nn + col] = f2b(v);
        else           ((float*)Cout)[(size_t)(row + q)*Nn + col] = v;
      }
    }
}

// ---------------- per-head LayerNorm of q,k (vectorized short8) -------------
// Block = 2 rows; wave = (row, q|k); lane covers 8 d of head (lane>>3)+8c.
// 16B loads/stores, 3-level shfl reduce within 8-lane head groups.
// k-centering is softmax-invariant -> skipped; Q pre-scaled to exp2 domain.
__global__ __launch_bounds__(256) void ln_qk(
    const u16* __restrict__ qkv,
    const float* __restrict__ qw, const float* __restrict__ qb,
    const float* __restrict__ kw, const float* __restrict__ kb,
    u16* __restrict__ Qs, u16* __restrict__ Kn)
{
  const int tid = threadIdx.x, wave = tid >> 6, lane = tid & 63;
  const int m = blockIdx.x*2 + (wave >> 1);      // row
  const int part = wave & 1;                     // 0=q, 1=k
  const int b = m >> 11, n = m & 2047;
  const float* wv = part ? kw : qw;
  const float* bv = part ? kb : qb;
  u16* dst = part ? Kn : Qs;
  const float scale = part ? 1.f : QKSCALE;
  const u16* base = qkv + (size_t)m*C3 + part*CDIM;
  const int d0 = (lane & 7) * 8;
  float wl[8], bl[8];
#pragma unroll
  for (int j = 0; j < 8; ++j) { wl[j] = wv[d0+j]*scale; bl[j] = bv[d0+j]*scale; }
#pragma unroll
  for (int c = 0; c < 2; ++c) {
    int h = c*8 + (lane >> 3);
    s16x8 v = *(const s16x8*)(base + c*512 + lane*8);
    float f[8]; float s = 0.f, s2 = 0.f;
#pragma unroll
    for (int j = 0; j < 8; ++j) {
      f[j] = b2f((u16)v[j]); s += f[j]; s2 += f[j]*f[j];
    }
#pragma unroll
    for (int off = 1; off < 8; off <<= 1) {
      s += __shfl_xor(s, off, 64); s2 += __shfl_xor(s2, off, 64);
    }
    float mu = s*(1.f/64.f);
    float rs = rsqrtf(s2*(1.f/64.f) - mu*mu + LN_EPS);
    union { u16 u[8]; uint4 q; } r;
#pragma unroll
    for (int j = 0; j < 8; ++j)
      r.u[j] = f2b((f[j]-mu)*rs*wl[j] + bl[j]);
    *(uint4*)(dst + ((size_t)(b*NHEAD+h)*SEQ + n)*HDIM + d0) = r.q;
  }
}

// ---------------- V transpose: qkv v-part -> Vt [B,H,D,N] bf16 -------------
__global__ __launch_bounds__(256) void v_transpose(
    const u16* __restrict__ qkv, u16* __restrict__ Vt)
{
  __shared__ u16 t[64][80];            // +16 pad
  int bh = blockIdx.x, j0 = blockIdx.y * 64;
  int b = bh >> 4, h = bh & 15;
  int tid = threadIdx.x;
  int nl = tid >> 2, ch = tid & 3;
  const u16* src = qkv + (size_t)(b*SEQ + j0 + nl)*C3 + 2*CDIM + h*HDIM + ch*16;
  *(uint4*)&t[nl][ch*16]     = *(const uint4*)src;
  *(uint4*)&t[nl][ch*16 + 8] = *(const uint4*)(src + 8);
  __syncthreads();
  int d = tid >> 2, nc = tid & 3;
  u16 o[16];
#pragma unroll
  for (int i = 0; i < 16; ++i) o[i] = t[nc*16 + i][d];
  u16* dst = Vt + ((size_t)(bh*HDIM + d))*SEQ + j0 + nc*16;
  *(uint4*)dst       = *(uint4*)&o[0];
  *(uint4*)(dst + 8) = *(uint4*)&o[8];
}

// ---------------- flash attention (T15 two-tile pipeline) -------------------
// 4 waves x QBLK=32 q-rows = 128 q/block; KV tiles of 64; grid 512 blocks.
// XCD chunked swizzle (R5/R7-proven: FETCH 69.7 -> 12.3 MB).
// R8: dependency-chain attack (R7 diagnosis: nothing saturated at 2 w/SIMD).
// 3 LDS buffers; iter t: QK(t+1) first [staged 2 iters ago, confirmed by last
// barrier], then PV(t) and softmax(t+1) emitted adjacently — independent, so
// the scheduler fills PV's MFMA shadows with softmax VALU (T15, m214 v36).
// Loop state: pfC = P-fragments of tile t (16 VGPR).
// Swapped QK^T (S^T = K*Q^T, lane = q-row), no-max exp2 softmax (LN bounds
// |logit| <= 8), P^T via v_cvt_pk_bf16_f32 + v_permlane32_swap_b32.
__global__ __launch_bounds__(256) void flash_attn(
    const u16* __restrict__ Qs, const u16* __restrict__ Kn,
    const u16* __restrict__ Vt, u16* __restrict__ Oa)
{
  __shared__ u16 Kt[3][64*64];     // [kv][d] swizzled, 3x8KB
  __shared__ u16 Vs[3][64*64];     // [d][kv] swizzled, 3x8KB
  const int tid = threadIdx.x, wave = tid >> 6, lane = tid & 63;
  const int l31 = lane & 31, hi = lane >> 5;
  const int bid0 = blockIdx.x + blockIdx.y*16;     // 512 blocks
  const int nid  = (bid0 & 7)*64 + (bid0 >> 3);    // chunked XCD swizzle
  const int bh   = nid >> 4;
  const int q0   = (nid & 15)*128 + wave*32;
  const int sw = l31 & 7;

  // Q^T B-fragments: lane holds Q[q0+l31][ks*16 + hi*8 + j], j=0..7
  const u16* Qrow = Qs + ((size_t)bh*SEQ + q0 + l31)*HDIM + hi*8;
  s16x8 qf[4];
#pragma unroll
  for (int ks = 0; ks < 4; ++ks)
    qf[ks] = *(const s16x8*)(Qrow + ks*16);

  f32x16 o0 = {}, o1 = {};
  float l_run = 0.f;

  const u16* Kg = Kn + (size_t)bh*SEQ*HDIM;
  const u16* Vg = Vt + (size_t)bh*HDIM*SEQ;

  // staging: 512 x 16B chunks per K (and V) buffer; 2 issues/wave each
  auto STAGE = [&](int jb, int buf) {
#pragma unroll
    for (int i = 0; i < 2; ++i) {
      int ci = (i*4 + wave)*64 + lane;
      int row = ci >> 3, ch = ci & 7;
      int chs = ch ^ (row & 7);               // pre-swizzled source
      G2L16(Kg + (size_t)(jb + row)*HDIM + chs*8, Kt[buf] + (i*4 + wave)*512);
      G2L16(Vg + (size_t)row*SEQ + jb + chs*8,    Vs[buf] + (i*4 + wave)*512);
    }
  };

  // S^T = K * Q^T : two 32-kv fragments (rows kv, cols q=l31)
  auto QK = [&](const u16* Kb, f32x16& s0, f32x16& s1) {
    __builtin_amdgcn_s_setprio(1);
#pragma unroll
    for (int ks = 0; ks < 4; ++ks) {
      int ch = ((ks*2 + hi) ^ sw) * 8;
      s16x8 k0 = *(const s16x8*)(Kb + l31*64 + ch);
      s16x8 k1 = *(const s16x8*)(Kb + (32 + l31)*64 + ch);
      s0 = mfma32(k0, qf[ks], s0);
      s1 = mfma32(k1, qf[ks], s1);
    }
    __builtin_amdgcn_s_setprio(0);
  };

  // P = exp2(S); l += tree-sum; pack P^T B-frags (cvt_pk + permlane32_swap)
  auto SM = [&](const f32x16& s0, const f32x16& s1, s16x8* pf) {
    float p0[16], p1[16];
#pragma unroll
    for (int i = 0; i < 16; ++i) p0[i] = fexp2(s0[i]);
#pragma unroll
    for (int i = 0; i < 16; ++i) p1[i] = fexp2(s1[i]);
    float s8[8];
#pragma unroll
    for (int i = 0; i < 8; ++i) s8[i] = (p0[i] + p0[i+8]) + (p1[i] + p1[i+8]);
    l_run += ((s8[0]+s8[1]) + (s8[2]+s8[3])) + ((s8[4]+s8[5]) + (s8[6]+s8[7]));
#pragma unroll
    for (int f = 0; f < 2; ++f) {
      const float* pp = f ? p1 : p0;
      unsigned pk[4][2];
#pragma unroll
      for (int q = 0; q < 4; ++q)
#pragma unroll
        for (int i = 0; i < 2; ++i)
          asm("v_cvt_pk_bf16_f32 %0, %1, %2"
              : "=v"(pk[q][i]) : "v"(pp[4*q+2*i]), "v"(pp[4*q+2*i+1]));
#pragma unroll
      for (int kc = 0; kc < 2; ++kc) {
        union { unsigned u[4]; s16x8 v; } bfu;
#pragma unroll
        for (int i = 0; i < 2; ++i) {
          unsigned x = pk[2*kc][i], y = pk[2*kc+1][i];
          asm("v_permlane32_swap_b32 %0, %1" : "+v"(x), "+v"(y));
          bfu.u[i] = x; bfu.u[2+i] = y;
        }
        pf[2*f+kc] = bfu.v;
      }
    }
  };

  // O^T += V^T * P^T   (rows d, cols q=l31)
  auto PV = [&](const u16* Vb, const s16x8* pf) {
    __builtin_amdgcn_s_setprio(1);
#pragma unroll
    for (int s = 0; s < 4; ++s) {
      int ch = ((s*2 + hi) ^ sw) * 8;
      s16x8 v0 = *(const s16x8*)(Vb + l31*64 + ch);
      s16x8 v1 = *(const s16x8*)(Vb + (32 + l31)*64 + ch);
      o0 = mfma32(v0, pf[s], o0);
      o1 = mfma32(v1, pf[s], o1);
    }
    __builtin_amdgcn_s_setprio(0);
  };

  const int NT = SEQ/64;           // 32
  // prologue: tiles 0,1 staged; softmax(0) done before entering steady state
  STAGE(0, 0);
  __syncthreads();                 // tile 0 resident
  STAGE(64, 1);                    // in flight
  s16x8 pfC[4];
  {
    f32x16 s0 = {}, s1 = {};
    QK(Kt[0], s0, s1);
    SM(s0, s1, pfC);
  }
  __syncthreads();                 // tile 1 resident
  STAGE(128, 2);                   // in flight

  // steady state: at top of iter t, buf[t%3]=tile t, buf[(t+1)%3]=tile t+1
  // resident; stage(t+2) in flight; pfC = pf(t).
  for (int t = 0; t < NT-1; ++t) {
    f32x16 n0 = {}, n1 = {};
    QK(Kt[(t+1)%3], n0, n1);       // next tile's scores
    s16x8 pfN[4];
    PV(Vs[t%3], pfC);              // current tile's PV ...
    SM(n0, n1, pfN);               // ... overlaps next tile's softmax
    __syncthreads();               // drains stage(t+2) -> resident
    if (t + 3 < NT) STAGE((t+3)*64, (t+3)%3);  // overwrites tile t: done above
#pragma unroll
    for (int i = 0; i < 4; ++i) pfC[i] = pfN[i];
  }
  PV(Vs[(NT-1)%3], pfC);           // epilogue tile

  // epilogue: O^T value r of frag df sits at d = (r&3) + 8*(r>>2) + 4*hi + 32*df
  float l_all = l_run + __shfl_xor(l_run, 32, 64);
  float inv = 1.f / l_all;
  int b = bh >> 4, h = bh & 15;
  u16* dst = Oa + ((size_t)(b*SEQ + q0 + l31))*CDIM + h*HDIM;
#pragma unroll
  for (int df = 0; df < 2; ++df)
#pragma unroll
    for (int q2 = 0; q2 < 4; ++q2) {
      float a0, a1, a2, a3;
      if (df) { a0=o1[4*q2]; a1=o1[4*q2+1]; a2=o1[4*q2+2]; a3=o1[4*q2+3]; }
      else    { a0=o0[4*q2]; a1=o0[4*q2+1]; a2=o0[4*q2+2]; a3=o0[4*q2+3]; }
      a0 *= inv; a1 *= inv; a2 *= inv; a3 *= inv;
      unsigned w0, w1;
      asm("v_cvt_pk_bf16_f32 %0, %1, %2" : "=v"(w0) : "v"(a0), "v"(a1));
      asm("v_cvt_pk_bf16_f32 %0, %1, %2" : "=v"(w1) : "v"(a2), "v"(a3));
      uint2 st; st.x = w0; st.y = w1;
      *(uint2*)(dst + df*32 + q2*8 + hi*4) = st;
    }
}

// ---------------- launch ----------------------------------------------------
extern "C" void kernel_launch(void* const* d_in, const int* in_sizes, int n_in,
                              void* d_out, int out_size, void* d_ws, size_t ws_size,
                              hipStream_t stream)
{
  const float* x      = (const float*)d_in[0];
  const float* qkv_w  = (const float*)d_in[1];
  const float* qnw    = (const float*)d_in[2];
  const float* qnb    = (const float*)d_in[3];
  const float* knw    = (const float*)d_in[4];
  const float* knb    = (const float*)d_in[5];
  const float* proj_w = (const float*)d_in[6];
  const float* proj_b = (const float*)d_in[7];
  float* out = (float*)d_out;

  char* ws = (char*)d_ws;                     // 72 MB used
  u16* xb    = (u16*)(ws);                    //  8 MB  x bf16
  u16* wqkv  = (u16*)(ws + (8ull  << 20));    //  6 MB  qkv_w bf16
  u16* wproj = (u16*)(ws + (14ull << 20));    //  2 MB  proj_w bf16
  u16* qkvb  = (u16*)(ws + (16ull << 20));    // 24 MB  qkv out bf16
  u16* Qsb   = (u16*)(ws + (40ull << 20));    //  8 MB  [B,H,N,D]
  u16* Knb   = (u16*)(ws + (48ull << 20));    //  8 MB  [B,H,N,D]
  u16* Vtb   = (u16*)(ws + (56ull << 20));    //  8 MB  [B,H,D,N]
  u16* Oab   = (u16*)(ws + (64ull << 20));    //  8 MB  attn out [M][C]

  cast_all<<<(XSEG + W1SEG + W2SEG)/256, 256, 0, stream>>>(
      x, qkv_w, proj_w, xb, wqkv, wproj);

  gemm_nt<true, false><<<dim3(MTOT/128, C3/128), 256, 0, stream>>>(
      xb, wqkv, qkvb, nullptr, MTOT, C3, CDIM);

  ln_qk<<<MTOT/2, 256, 0, stream>>>(qkvb, qnw, qnb, knw, knb, Qsb, Knb);
  v_transpose<<<dim3(NBATCH*NHEAD, SEQ/64), 256, 0, stream>>>(qkvb, Vtb);

  flash_attn<<<dim3(SEQ/128, NBATCH*NHEAD), 256, 0, stream>>>(Qsb, Knb, Vtb, Oab);

  gemm_nt<false, true><<<dim3(MTOT/128, CDIM/128), 256, 0, stream>>>(
      Oab, wproj, out, proj_b, MTOT, CDIM, CDIM);
}